// Round 15
// baseline (947.515 us; speedup 1.0000x reference)
//
#include <hip/hip_runtime.h>
#include <hip/hip_bf16.h>
#include <math.h>

#define N_ROWS 131072
#define DIN    768
#define DHID   512
#define DCODE  256
#define KC     512
#define NFUSE  768      // KC + DCODE (dots cols + z cols)
#define TAU1   1.5f     // tier-1 screen (plain h1 + plain dots; validated r9/r13)
#define TAU2   5e-3f    // tier-2 screen (split-2 numerics; validated r6/7/8/10)
#define CAP    32768    // tier-2 row capacity (overflow -> bitwise recompute)

typedef short short8 __attribute__((ext_vector_type(8)));
typedef float f32x4  __attribute__((ext_vector_type(4)));
typedef unsigned int   u32;
typedef unsigned short u16;

__device__ __forceinline__ void gload16(const void* g, void* l) {
    __builtin_amdgcn_global_load_lds(
        (const __attribute__((address_space(1))) u32*)g,
        (__attribute__((address_space(3))) u32*)l, 16, 0, 0);
}

__device__ __forceinline__ u16 f2bf(float f) {
    u32 u = __builtin_bit_cast(u32, f);
    return (u16)((u + 0x7fffu + ((u >> 16) & 1u)) >> 16);
}
// hardware RTNE f32->bf16 (v_cvt); bit-compatible with f2bf for the
// lenient/screened paths (any RTNE is within the tau1 error budget)
__device__ __forceinline__ short f2bf_hw(float f) {
    __hip_bfloat16 h = __float2bfloat16(f);
    return __builtin_bit_cast(short, h);
}
__device__ __forceinline__ float bf2f(u16 h) {
    u32 u = ((u32)h) << 16;
    return __builtin_bit_cast(float, u);
}

// m157-form bijective XCD swizzle (all grids have nwg % 8 == 0)
__device__ __forceinline__ void xcd_swizzle(int& bxs, int& bys) {
    const int GX  = gridDim.x;
    const int nwg = GX * gridDim.y;
    const int lid = blockIdx.y * GX + blockIdx.x;
    const int chunk = nwg >> 3;
    const int nlid  = (lid & 7) * chunk + (lid >> 3);
    bxs = nlid % GX;
    bys = nlid / GX;
}

// hi/lo bf16 split of a float4, written to two 8B LDS slots
__device__ __forceinline__ void split_write(char* hidst, char* lodst, float4 v) {
    u16 h0 = f2bf(v.x), h1 = f2bf(v.y), h2 = f2bf(v.z), h3 = f2bf(v.w);
    u16 l0 = f2bf(__fsub_rn(v.x, bf2f(h0)));
    u16 l1 = f2bf(__fsub_rn(v.y, bf2f(h1)));
    u16 l2 = f2bf(__fsub_rn(v.z, bf2f(h2)));
    u16 l3 = f2bf(__fsub_rn(v.w, bf2f(h3)));
    ushort4 hi; hi.x = h0; hi.y = h1; hi.z = h2; hi.w = h3;
    ushort4 lo; lo.x = l0; lo.y = l1; lo.z = l2; lo.w = l3;
    *(ushort4*)hidst = hi;
    *(ushort4*)lodst = lo;
}

// ---------------------------------------------------------------------------
// Tier-1 H1: plain bf16 MFMA, f32 A-source (hw cvt + swizzled ds_write).
// 128x128, BK=64, single-buffer 32KB, (256,3) proven allocation.
// ---------------------------------------------------------------------------
__global__ __launch_bounds__(256, 3)
void h1_plain(const float* __restrict__ x, const u16* __restrict__ W1T,
              const float* __restrict__ b1, u16* __restrict__ h1b,
              int M, int N, int K)
{
    __shared__ char lds[32768];
    const int t = threadIdx.x, lane = t & 63, wid = t >> 6;
    const int wm = wid >> 1, wn = wid & 1;
    int bxs, bys; xcd_swizzle(bxs, bys);
    const int bm = bys * 128, bn = bxs * 128;

    const int sr = lane >> 3;
    const int sc = ((lane & 7) ^ sr) * 8;
    const u16* bptr[4];
    #pragma unroll
    for (int c = 0; c < 4; c++) {
        int brow = bn + 8 * (wid * 4 + c) + sr;
        bptr[c] = W1T + (size_t)brow * K + sc;
    }
    const float* asrc[4];
    int albyte[4];
    #pragma unroll
    for (int c = 0; c < 4; c++) {
        int id = c * 256 + t;           // row(0..127) x slot(0..7)
        int row = id >> 3, g = id & 7;
        asrc[c]   = x + (size_t)(bm + row) * K + g * 8;
        albyte[c] = row * 128 + ((g ^ (row & 7)) << 4);
    }

    f32x4 acc[4][4];
    #pragma unroll
    for (int i = 0; i < 4; i++)
        #pragma unroll
        for (int j = 0; j < 4; j++) acc[i][j] = (f32x4)0.f;

    const int koff0 = (16 * (lane >> 4))      ^ ((lane & 7) << 4);
    const int koff1 = (64 + 16 * (lane >> 4)) ^ ((lane & 7) << 4);
    const int arow_rd = wm * 64 + (lane & 15);
    const int brow_rd = wn * 64 + (lane & 15);

    const int NT = K >> 6;   // 12
    for (int tt = 0; tt < NT; tt++) {
        __syncthreads();
        const int k0 = tt << 6;
        #pragma unroll
        for (int c = 0; c < 4; c++)
            gload16(bptr[c] + k0, lds + 16384 + (wid * 4 + c) * 1024);
        #pragma unroll
        for (int c = 0; c < 4; c++) {
            float4 v0 = *(const float4*)(asrc[c] + k0);
            float4 v1 = *(const float4*)(asrc[c] + k0 + 4);
            short8 p;
            p[0] = f2bf_hw(v0.x); p[1] = f2bf_hw(v0.y);
            p[2] = f2bf_hw(v0.z); p[3] = f2bf_hw(v0.w);
            p[4] = f2bf_hw(v1.x); p[5] = f2bf_hw(v1.y);
            p[6] = f2bf_hw(v1.z); p[7] = f2bf_hw(v1.w);
            *(short8*)(lds + albyte[c]) = p;
        }
        __syncthreads();
        char* ldsA = lds;
        char* ldsB = lds + 16384;
        #pragma unroll
        for (int kk = 0; kk < 2; kk++) {
            const int ko = kk ? koff1 : koff0;
            short8 af[4], bfr[4];
            #pragma unroll
            for (int i = 0; i < 4; i++)
                af[i]  = *(const short8*)(ldsA + (arow_rd + i * 16) * 128 + ko);
            #pragma unroll
            for (int j = 0; j < 4; j++)
                bfr[j] = *(const short8*)(ldsB + (brow_rd + j * 16) * 128 + ko);
            #pragma unroll
            for (int i = 0; i < 4; i++)
                #pragma unroll
                for (int j = 0; j < 4; j++)
                    acc[i][j] = __builtin_amdgcn_mfma_f32_16x16x32_bf16(
                        af[i], bfr[j], acc[i][j], 0, 0, 0);
        }
    }

    const int er = (lane >> 4) * 4, ec = lane & 15;
    #pragma unroll
    for (int j = 0; j < 4; j++) {
        int col  = bn + wn * 64 + j * 16 + ec;
        float bb = b1[col];
        #pragma unroll
        for (int i = 0; i < 4; i++) {
            #pragma unroll
            for (int e = 0; e < 4; e++) {
                int r   = bm + wm * 64 + i * 16 + er + e;
                float v = fmaxf(acc[i][j][e] + bb, 0.f);
                h1b[(size_t)r * N + col] = f2bf(v);
            }
        }
    }
}

// ---------------------------------------------------------------------------
// Split-2 bf16 MFMA GEMM (tier-2 only). 128x128, BK=32, 32KB LDS, (256,3).
// ecnt: early-exit row count (blocks with bm >= *ecnt return immediately,
// making tier-2 cost scale with the actual contested count).
// EPI=0: A = f32 (gathered x), epilogue relu+bias -> hi/lo bf16.
// EPI=1: A = bf16 hi/lo pair; epilogue dist top-2 lex-min strip partials.
// ---------------------------------------------------------------------------
template<int EPI>
__global__ __launch_bounds__(256, 3)
void split2_gemm(const float* __restrict__ Af32,
                 const u16* __restrict__ Ahi, const u16* __restrict__ Alo,
                 const u16* __restrict__ Bhi, const u16* __restrict__ Blo,
                 const float* __restrict__ bias,
                 const float* __restrict__ cnorm,
                 u16* __restrict__ Chi, u16* __restrict__ Clo,
                 float* __restrict__ pd1, int* __restrict__ pi1,
                 float* __restrict__ pd2,
                 const int* __restrict__ ecnt,
                 int M, int N, int K)
{
    __shared__ char lds[32768];
    const int t = threadIdx.x, lane = t & 63, wid = t >> 6;
    const int wm = wid >> 1, wn = wid & 1;
    int bxs, bys; xcd_swizzle(bxs, bys);
    const int bm = bys * 128, bn = bxs * 128;
    if (ecnt && bm >= *ecnt) return;   // uniform early-exit (before any barrier)

    const int sr = lane >> 3, qq = lane & 7, sl = qq ^ sr;
    const u16* bsrc[4];
    #pragma unroll
    for (int c = 0; c < 4; c++) {
        int row = bn + (wid * 4 + c) * 8 + sr;
        const u16* base = (sl < 4) ? Bhi : Blo;
        bsrc[c] = base + (size_t)row * K + (sl & 3) * 8;
    }
    const u16* asrc[4];
    const float* a32src[4];
    int adhi[4], adlo[4];
    if constexpr (EPI == 1) {
        #pragma unroll
        for (int c = 0; c < 4; c++) {
            int row = bm + (wid * 4 + c) * 8 + sr;
            const u16* base = (sl < 4) ? Ahi : Alo;
            asrc[c] = base + (size_t)row * K + (sl & 3) * 8;
        }
    } else {
        #pragma unroll
        for (int c = 0; c < 4; c++) {
            int id = c * 256 + t;
            int row = id >> 3, k4 = id & 7;
            a32src[c] = Af32 + (size_t)(bm + row) * K + k4 * 4;
            int s = k4 >> 1, hf = k4 & 1;
            adhi[c] = row * 128 + ((s ^ (row & 7)) << 4) + hf * 8;
            adlo[c] = row * 128 + (((s | 4) ^ (row & 7)) << 4) + hf * 8;
        }
    }

    f32x4 acc[4][4];
    #pragma unroll
    for (int i = 0; i < 4; i++)
        #pragma unroll
        for (int j = 0; j < 4; j++) acc[i][j] = (f32x4)0.f;

    const int fr = lane & 15, sw = lane & 7;
    const int offhi = (((lane >> 4) ^ sw) << 4);
    const int offlo = ((((lane >> 4) | 4) ^ sw) << 4);
    const int arow = wm * 64 + fr, brow = wn * 64 + fr;
    const int NT = K >> 5;

    for (int tt = 0; tt < NT; tt++) {
        __syncthreads();
        const int kadv = tt * 32;
        #pragma unroll
        for (int c = 0; c < 4; c++)
            gload16(bsrc[c] + kadv, lds + 16384 + (wid * 4 + c) * 1024);
        if constexpr (EPI == 1) {
            #pragma unroll
            for (int c = 0; c < 4; c++)
                gload16(asrc[c] + kadv, lds + (wid * 4 + c) * 1024);
        } else {
            #pragma unroll
            for (int c = 0; c < 4; c++) {
                float4 v = *(const float4*)(a32src[c] + kadv);
                split_write(lds + adhi[c], lds + adlo[c], v);
            }
        }
        __syncthreads();
        char* ab  = lds;
        char* bb2 = lds + 16384;
        short8 ah[4], al[4];
        #pragma unroll
        for (int i = 0; i < 4; i++) {
            ah[i] = *(const short8*)(ab + ((arow + i * 16) << 7) + offhi);
            al[i] = *(const short8*)(ab + ((arow + i * 16) << 7) + offlo);
        }
        #pragma unroll
        for (int j = 0; j < 4; j++) {
            short8 bh = *(const short8*)(bb2 + ((brow + j * 16) << 7) + offhi);
            short8 bl = *(const short8*)(bb2 + ((brow + j * 16) << 7) + offlo);
            #pragma unroll
            for (int i = 0; i < 4; i++) {
                acc[i][j] = __builtin_amdgcn_mfma_f32_16x16x32_bf16(ah[i], bh, acc[i][j], 0, 0, 0);
                acc[i][j] = __builtin_amdgcn_mfma_f32_16x16x32_bf16(al[i], bh, acc[i][j], 0, 0, 0);
                acc[i][j] = __builtin_amdgcn_mfma_f32_16x16x32_bf16(ah[i], bl, acc[i][j], 0, 0, 0);
            }
        }
    }

    if constexpr (EPI == 1) {
        const int ec = lane & 15, g = lane >> 4;
        float cnv[4], bcv[4];
        #pragma unroll
        for (int j = 0; j < 4; j++) {
            int c = bn + wn * 64 + j * 16 + ec;
            cnv[j] = cnorm[c]; bcv[j] = bias[c];
        }
        const int strip = bxs * 2 + wn;
        #pragma unroll
        for (int i = 0; i < 4; i++) {
            #pragma unroll
            for (int e = 0; e < 4; e++) {
                float d1 = INFINITY, d2 = INFINITY; int i1 = 0x7fffffff;
                #pragma unroll
                for (int j = 0; j < 4; j++) {
                    int c = bn + wn * 64 + j * 16 + ec;
                    float d = __fsub_rn(cnv[j],
                              __fmul_rn(2.0f, __fadd_rn(acc[i][j][e], bcv[j])));
                    if (d < d1 || (d == d1 && c < i1)) { d2 = d1; d1 = d; i1 = c; }
                    else if (d < d2) d2 = d;
                }
                #pragma unroll
                for (int m = 1; m < 16; m <<= 1) {
                    float od1 = __shfl_xor(d1, m);
                    int   oi1 = __shfl_xor(i1, m);
                    float od2 = __shfl_xor(d2, m);
                    if (od1 < d1 || (od1 == d1 && oi1 < i1)) {
                        d2 = fminf(d1, od2); d1 = od1; i1 = oi1;
                    } else d2 = fminf(d2, od1);
                }
                if (ec == 0) {
                    int r = bm + wm * 64 + i * 16 + g * 4 + e;
                    pd1[(size_t)strip * M + r] = d1;
                    pi1[(size_t)strip * M + r] = i1;
                    pd2[(size_t)strip * M + r] = d2;
                }
            }
        }
        return;
    } else {
        const int er = (lane >> 4) * 4, ec = lane & 15;
        #pragma unroll
        for (int j = 0; j < 4; j++) {
            int col = bn + wn * 64 + j * 16 + ec;
            float bb = bias[col];
            #pragma unroll
            for (int i = 0; i < 4; i++) {
                #pragma unroll
                for (int e = 0; e < 4; e++) {
                    int r = bm + wm * 64 + i * 16 + er + e;
                    float v = fmaxf(__fadd_rn(acc[i][j][e], bb), 0.f);
                    u16 hi = f2bf(v);
                    u16 lo = f2bf(__fsub_rn(v, bf2f(hi)));
                    Chi[(size_t)r * N + col] = hi;
                    Clo[(size_t)r * N + col] = lo;
                }
            }
        }
    }
}

// ---------------------------------------------------------------------------
// Tier-1 DOTS+Z: plain bf16 MFMA on h1b. 128x128, BK=64, 32KB, (256,3).
// Col-blocks 0-3: dist top-2 strip partials. Col-blocks 4-5: znorm partials.
// ---------------------------------------------------------------------------
__global__ __launch_bounds__(256, 3)
void dots_gemm(const u16* __restrict__ A, const u16* __restrict__ BT,
               const float* __restrict__ bias, const float* __restrict__ cnorm,
               float* __restrict__ pd1, int* __restrict__ pi1,
               float* __restrict__ pd2, float* __restrict__ pzn,
               int M, int N, int K)
{
    __shared__ char lds[32768];
    const int t = threadIdx.x, lane = t & 63, wid = t >> 6;
    const int wm = wid >> 1, wn = wid & 1;
    int bxs, bys; xcd_swizzle(bxs, bys);
    const int bm = bys * 128, bn = bxs * 128;

    const int sr = lane >> 3;
    const int sc = ((lane & 7) ^ sr) * 8;
    const u16* aptr[4];
    const u16* bptr[4];
    #pragma unroll
    for (int c = 0; c < 4; c++) {
        int gc = wid * 4 + c;
        aptr[c] = A  + (size_t)(bm + 8 * gc + sr) * K + sc;
        bptr[c] = BT + (size_t)(bn + 8 * gc + sr) * K + sc;
    }

    f32x4 acc[4][4];
    #pragma unroll
    for (int i = 0; i < 4; i++)
        #pragma unroll
        for (int j = 0; j < 4; j++) acc[i][j] = (f32x4)0.f;

    const int koff0 = (16 * (lane >> 4))      ^ ((lane & 7) << 4);
    const int koff1 = (64 + 16 * (lane >> 4)) ^ ((lane & 7) << 4);
    const int arow_rd = wm * 64 + (lane & 15);
    const int brow_rd = wn * 64 + (lane & 15);

    const int NT = K >> 6;   // 8
    for (int tt = 0; tt < NT; tt++) {
        __syncthreads();
        const int k0 = tt << 6;
        #pragma unroll
        for (int c = 0; c < 4; c++) {
            int gc = wid * 4 + c;
            gload16(aptr[c] + k0, lds + gc * 1024);
            gload16(bptr[c] + k0, lds + 16384 + gc * 1024);
        }
        __syncthreads();
        char* ldsA = lds;
        char* ldsB = lds + 16384;
        #pragma unroll
        for (int kk = 0; kk < 2; kk++) {
            const int ko = kk ? koff1 : koff0;
            short8 af[4], bfr[4];
            #pragma unroll
            for (int i = 0; i < 4; i++)
                af[i]  = *(const short8*)(ldsA + (arow_rd + i * 16) * 128 + ko);
            #pragma unroll
            for (int j = 0; j < 4; j++)
                bfr[j] = *(const short8*)(ldsB + (brow_rd + j * 16) * 128 + ko);
            #pragma unroll
            for (int i = 0; i < 4; i++)
                #pragma unroll
                for (int j = 0; j < 4; j++)
                    acc[i][j] = __builtin_amdgcn_mfma_f32_16x16x32_bf16(
                        af[i], bfr[j], acc[i][j], 0, 0, 0);
        }
    }

    const int ec = lane & 15, g = lane >> 4;
    if (bxs < 4) {
        float cnv[4], bcv[4];
        #pragma unroll
        for (int j = 0; j < 4; j++) {
            int c = bn + wn * 64 + j * 16 + ec;
            cnv[j] = cnorm[c]; bcv[j] = bias[c];
        }
        const int strip = bxs * 2 + wn;
        #pragma unroll
        for (int i = 0; i < 4; i++) {
            #pragma unroll
            for (int e = 0; e < 4; e++) {
                float d1 = INFINITY, d2 = INFINITY; int i1 = 0x7fffffff;
                #pragma unroll
                for (int j = 0; j < 4; j++) {
                    int c = bn + wn * 64 + j * 16 + ec;
                    float d = __fsub_rn(cnv[j],
                              __fmul_rn(2.0f, __fadd_rn(acc[i][j][e], bcv[j])));
                    if (d < d1 || (d == d1 && c < i1)) { d2 = d1; d1 = d; i1 = c; }
                    else if (d < d2) d2 = d;
                }
                #pragma unroll
                for (int m = 1; m < 16; m <<= 1) {
                    float od1 = __shfl_xor(d1, m);
                    int   oi1 = __shfl_xor(i1, m);
                    float od2 = __shfl_xor(d2, m);
                    if (od1 < d1 || (od1 == d1 && oi1 < i1)) {
                        d2 = fminf(d1, od2); d1 = od1; i1 = oi1;
                    } else d2 = fminf(d2, od1);
                }
                if (ec == 0) {
                    int r = bm + wm * 64 + i * 16 + g * 4 + e;
                    pd1[(size_t)strip * M + r] = d1;
                    pi1[(size_t)strip * M + r] = i1;
                    pd2[(size_t)strip * M + r] = d2;
                }
            }
        }
    } else {
        float bcv[4];
        #pragma unroll
        for (int j = 0; j < 4; j++)
            bcv[j] = bias[bn + wn * 64 + j * 16 + ec];
        const int zs = (bxs - 4) * 2 + wn;
        #pragma unroll
        for (int i = 0; i < 4; i++) {
            #pragma unroll
            for (int e = 0; e < 4; e++) {
                float s = 0.f;
                #pragma unroll
                for (int j = 0; j < 4; j++) {
                    float zv = acc[i][j][e] + bcv[j];
                    s = fmaf(zv, zv, s);
                }
                #pragma unroll
                for (int m = 1; m < 16; m <<= 1) s += __shfl_xor(s, m);
                if (ec == 0) {
                    int r = bm + wm * 64 + i * 16 + g * 4 + e;
                    pzn[(size_t)zs * M + r] = s;
                }
            }
        }
    }
}

// ---------------------------------------------------------------------------
// Plain bf16 MFMA GEMM (tiny R-table GEMMs; lenient).
// ---------------------------------------------------------------------------
template<bool RELU, bool OUT_BF16>
__global__ __launch_bounds__(256, 3)
void mfma_gemm(const u16* __restrict__ A, const u16* __restrict__ BT,
               const float* __restrict__ bias,
               void* __restrict__ Cout, int M, int N, int K)
{
    __shared__ char lds[32768];
    const int t    = threadIdx.x;
    const int lane = t & 63, wid = t >> 6;
    const int wm   = wid >> 1, wn = wid & 1;
    int bxs, bys;
    xcd_swizzle(bxs, bys);
    const int bm = bys * 128, bn = bxs * 128;

    const int sr = lane >> 3;
    const int sc = ((lane & 7) ^ sr) * 8;
    const u16* aptr[4];
    const u16* bptr[4];
    #pragma unroll
    for (int c = 0; c < 4; c++) {
        int gc   = wid * 4 + c;
        aptr[c] = A  + (size_t)(bm + 8 * gc + sr) * K + sc;
        bptr[c] = BT + (size_t)(bn + 8 * gc + sr) * K + sc;
    }

    f32x4 acc[4][4];
    #pragma unroll
    for (int i = 0; i < 4; i++)
        #pragma unroll
        for (int j = 0; j < 4; j++) acc[i][j] = (f32x4)0.f;

    const int koff0 = (16 * (lane >> 4))      ^ ((lane & 7) << 4);
    const int koff1 = (64 + 16 * (lane >> 4)) ^ ((lane & 7) << 4);
    const int arow_rd = wm * 64 + (lane & 15);
    const int brow_rd = wn * 64 + (lane & 15);

    const int NT = K >> 6;
    for (int tt = 0; tt < NT; tt++) {
        __syncthreads();
        const int k0 = tt << 6;
        #pragma unroll
        for (int c = 0; c < 4; c++) {
            int gc = wid * 4 + c;
            gload16(aptr[c] + k0, lds + gc * 1024);
            gload16(bptr[c] + k0, lds + 16384 + gc * 1024);
        }
        __syncthreads();
        char* ldsA = lds;
        char* ldsB = lds + 16384;
        #pragma unroll
        for (int kk = 0; kk < 2; kk++) {
            const int ko = kk ? koff1 : koff0;
            short8 af[4], bfr[4];
            #pragma unroll
            for (int i = 0; i < 4; i++)
                af[i]  = *(const short8*)(ldsA + (arow_rd + i * 16) * 128 + ko);
            #pragma unroll
            for (int j = 0; j < 4; j++)
                bfr[j] = *(const short8*)(ldsB + (brow_rd + j * 16) * 128 + ko);
            #pragma unroll
            for (int i = 0; i < 4; i++)
                #pragma unroll
                for (int j = 0; j < 4; j++)
                    acc[i][j] = __builtin_amdgcn_mfma_f32_16x16x32_bf16(
                        af[i], bfr[j], acc[i][j], 0, 0, 0);
        }
    }

    const int er = (lane >> 4) * 4;
    const int ec = lane & 15;
    #pragma unroll
    for (int j = 0; j < 4; j++) {
        int col  = bn + wn * 64 + j * 16 + ec;
        float bb = bias[col];
        #pragma unroll
        for (int i = 0; i < 4; i++) {
            #pragma unroll
            for (int e = 0; e < 4; e++) {
                int r   = bm + wm * 64 + i * 16 + er + e;
                float v = acc[i][j][e] + bb;
                if (RELU) v = fmaxf(v, 0.f);
                if (OUT_BF16) ((u16*)Cout)[(size_t)r * N + col]  = f2bf(v);
                else          ((float*)Cout)[(size_t)r * N + col] = v;
            }
        }
    }
}

// ---------------------------------------------------------------------------
// recon = R[idx[r]] broadcast-gather (R is 512x768 fp32, L2-resident).
// ---------------------------------------------------------------------------
__global__ __launch_bounds__(256)
void gather_out(const float* __restrict__ R, const int* __restrict__ idxi,
                float* __restrict__ out)
{
    int w    = (blockIdx.x * 256 + threadIdx.x) >> 6;
    int lane = threadIdx.x & 63;
    int nw   = (gridDim.x * 256) >> 6;
    for (int r = w; r < N_ROWS; r += nw) {
        int code = idxi[r];
        const float4* src = (const float4*)(R + (size_t)code * DIN);
        float4* dst = (float4*)(out + (size_t)r * DIN);
        dst[lane]       = src[lane];
        dst[lane + 64]  = src[lane + 64];
        dst[lane + 128] = src[lane + 128];
    }
}

// ---------------------------------------------------------------------------
// Gather contested x rows (f32, 768 each) into compact xg (first CAP).
// ---------------------------------------------------------------------------
__global__ __launch_bounds__(256)
void gather_x(const float* __restrict__ x, const int* __restrict__ list,
              const int* __restrict__ cnt, float* __restrict__ xg)
{
    int n1 = *cnt; if (n1 > CAP) n1 = CAP;
    int w    = (blockIdx.x * 256 + threadIdx.x) >> 6;
    int lane = threadIdx.x & 63;
    int nw   = (gridDim.x * 256) >> 6;
    for (int i = w; i < n1; i += nw) {
        int row = list[i];
        const float4* src = (const float4*)(x + (size_t)row * DIN);
        float4* dst = (float4*)(xg + (size_t)i * DIN);
        dst[lane]       = src[lane];
        dst[lane + 64]  = src[lane + 64];
        dst[lane + 128] = src[lane + 128];
    }
}

// ---------------------------------------------------------------------------
// Prep kernels
// ---------------------------------------------------------------------------
__global__ void transpose_cb_kernel(const float* __restrict__ cb, float* __restrict__ cbT)
{
    int tid = blockIdx.x * 256 + threadIdx.x;   // 512*256
    int k = tid >> 8;
    int d = tid & 255;
    cbT[(size_t)d * KC + k] = cb[(size_t)k * DCODE + d];
}

__global__ void cast_bf16_kernel(const float* __restrict__ in, u16* __restrict__ out, int n)
{
    int i = blockIdx.x * 256 + threadIdx.x;
    if (i < n) out[i] = f2bf(in[i]);
}

// in [K][N] fp32 -> out [N][K] bf16
__global__ void castT_bf16_kernel(const float* __restrict__ in, u16* __restrict__ out,
                                  int K, int N)
{
    int i = blockIdx.x * 256 + threadIdx.x;
    if (i >= K * N) return;
    int n = i / K, k = i - n * K;
    out[i] = f2bf(in[(size_t)k * N + n]);
}

// W1 [768][512] -> W1T hi/lo [512][768]  (hi == plain bf16 cast)
__global__ void prep_W1T(const float* __restrict__ W1, u16* __restrict__ Thi,
                         u16* __restrict__ Tlo)
{
    int id = blockIdx.x * 256 + threadIdx.x;    // 512*768
    if (id >= DHID * DIN) return;
    int n = id / DIN, k = id - n * DIN;
    float v = W1[(size_t)k * DHID + n];
    u16 hi = f2bf(v);
    Thi[id] = hi;
    Tlo[id] = f2bf(__fsub_rn(v, bf2f(hi)));
}

// Wfb rows 0-511: Wc[n][h] = fp64 sum W2[h][t]*cb[n][t] -> hi (Wfb) + lo
__global__ void prep_Wc(const float* __restrict__ W2, const float* __restrict__ cb,
                        u16* __restrict__ Thi, u16* __restrict__ Tlo)
{
    int id = blockIdx.x * 256 + threadIdx.x;    // 512*512
    int n = id & 511, h = id >> 9;
    double acc = 0.0;
    for (int tt2 = 0; tt2 < DCODE; tt2++)
        acc += (double)W2[(size_t)h * DCODE + tt2] * (double)cb[(size_t)n * DCODE + tt2];
    float v = (float)acc;
    u16 hi = f2bf(v);
    Thi[(size_t)n * DHID + h] = hi;
    Tlo[(size_t)n * DHID + h] = f2bf(__fsub_rn(v, bf2f(hi)));
}

// Wfb rows 512-767: W2 [512][256] -> Wfb[512+t2][h] bf16 (z cols, lenient)
__global__ void prep_W2T(const float* __restrict__ W2, u16* __restrict__ T)
{
    int id = blockIdx.x * 256 + threadIdx.x;    // 256*512
    if (id >= DCODE * DHID) return;
    int t2 = id >> 9, h = id & 511;
    T[(size_t)(KC + t2) * DHID + h] = f2bf(W2[(size_t)h * DCODE + t2]);
}

// bcf[0..511] = fp64 b2·cb[n]; bcf[512..767] = b2[n-512]
__global__ void prep_bcf(const float* __restrict__ b2, const float* __restrict__ cb,
                         float* __restrict__ bcf)
{
    int n = blockIdx.x * 256 + threadIdx.x;
    if (n >= NFUSE) return;
    if (n < KC) {
        double acc = 0.0;
        for (int tt2 = 0; tt2 < DCODE; tt2++)
            acc += (double)b2[tt2] * (double)cb[(size_t)n * DCODE + tt2];
        bcf[n] = (float)acc;
    } else {
        bcf[n] = b2[n - KC];
    }
}

// ||c_k||^2 replicating numpy float32 pairwise-summation bitwise (ref-exact).
__global__ void cnorm_np_kernel(const float* __restrict__ cb, float* __restrict__ cnorm)
{
    int k = blockIdx.x * 64 + threadIdx.x;
    if (k >= KC) return;
    const float* c = cb + (size_t)k * DCODE;
    float bsum[2];
    #pragma unroll
    for (int b = 0; b < 2; b++) {
        const float* a = c + b * 128;
        float r[8];
        #pragma unroll
        for (int j = 0; j < 8; j++) r[j] = __fmul_rn(a[j], a[j]);
        for (int i = 8; i < 128; i += 8)
            #pragma unroll
            for (int j = 0; j < 8; j++)
                r[j] = __fadd_rn(r[j], __fmul_rn(a[i + j], a[i + j]));
        bsum[b] = __fadd_rn(
            __fadd_rn(__fadd_rn(r[0], r[1]), __fadd_rn(r[2], r[3])),
            __fadd_rn(__fadd_rn(r[4], r[5]), __fadd_rn(r[6], r[7])));
    }
    cnorm[k] = __fadd_rn(bsum[0], bsum[1]);
}

// ---------------------------------------------------------------------------
// Tier-1 merge of 8 strip top-2 partials + 4 znorm partials; flag gap < TAU1.
// ---------------------------------------------------------------------------
__global__ void final_argmin_flag(const float* __restrict__ pd1,
                                  const int* __restrict__ pi1,
                                  const float* __restrict__ pd2,
                                  const float* __restrict__ pzn,
                                  float* __restrict__ idx_f,
                                  int* __restrict__ idx_i,
                                  float* __restrict__ rowloss,
                                  int* __restrict__ cnt,
                                  int* __restrict__ list)
{
    int r = blockIdx.x * 256 + threadIdx.x;
    if (r >= N_ROWS) return;
    float d1 = pd1[r]; int i1 = pi1[r]; float d2 = pd2[r];
    #pragma unroll
    for (int b = 1; b < 8; b++) {
        float od1 = pd1[(size_t)b * N_ROWS + r];
        int   oi1 = pi1[(size_t)b * N_ROWS + r];
        float od2 = pd2[(size_t)b * N_ROWS + r];
        if (od1 < d1 || (od1 == d1 && oi1 < i1)) {
            d2 = fminf(d1, od2); d1 = od1; i1 = oi1;
        } else d2 = fminf(d2, od1);
    }
    float zn = pzn[r] + pzn[(size_t)N_ROWS + r]
             + pzn[(size_t)2 * N_ROWS + r] + pzn[(size_t)3 * N_ROWS + r];
    idx_f[r]   = (float)i1;
    idx_i[r]   = i1;
    rowloss[r] = zn + d1;
    if (d2 - d1 < TAU1) {
        int p = atomicAdd(cnt, 1);
        list[p] = r;
    }
}

// ---------------------------------------------------------------------------
// Tier-2 merge: resolve gathered rows from split-2 strip partials; rows with
// gap < TAU2 (plus tier-1 overflow) go to the bitwise recompute list.
// ---------------------------------------------------------------------------
__global__ void merge2_flag(const float* __restrict__ pd1b,
                            const int* __restrict__ pi1b,
                            const float* __restrict__ pd2b,
                            const int* __restrict__ list,
                            const int* __restrict__ cnt1,
                            float* __restrict__ idx_f, int* __restrict__ idx_i,
                            int* __restrict__ cnt2, int* __restrict__ list2)
{
    int i = blockIdx.x * 256 + threadIdx.x;
    if (i >= CAP) return;
    int n1 = *cnt1; if (n1 > CAP) n1 = CAP;
    if (i >= n1) return;
    float d1 = pd1b[i]; int i1 = pi1b[i]; float d2 = pd2b[i];
    #pragma unroll
    for (int b = 1; b < 8; b++) {
        float od1 = pd1b[(size_t)b * CAP + i];
        int   oi1 = pi1b[(size_t)b * CAP + i];
        float od2 = pd2b[(size_t)b * CAP + i];
        if (od1 < d1 || (od1 == d1 && oi1 < i1)) {
            d2 = fminf(d1, od2); d1 = od1; i1 = oi1;
        } else d2 = fminf(d2, od1);
    }
    int row = list[i];
    idx_f[row] = (float)i1;
    idx_i[row] = i1;
    if (d2 - d1 < TAU2) {
        int p = atomicAdd(cnt2, 1);
        list2[p] = row;
    }
}

__global__ void overflow_append(const int* __restrict__ list,
                                const int* __restrict__ cnt1,
                                int* __restrict__ cnt2, int* __restrict__ list2)
{
    int i = CAP + blockIdx.x * 256 + threadIdx.x;
    if (i < *cnt1) {
        int p = atomicAdd(cnt2, 1);
        list2[p] = list[i];
    }
}

// ---------------------------------------------------------------------------
// Bitwise fp32 recompute for contested rows (exact round-2 chain numerics).
// ---------------------------------------------------------------------------
__global__ __launch_bounds__(512)
void recompute_kernel(const float* __restrict__ x,  const float* __restrict__ W1,
                      const float* __restrict__ b1, const float* __restrict__ W2,
                      const float* __restrict__ b2, const float* __restrict__ cbT,
                      const float* __restrict__ cnorm,
                      const int* __restrict__ cnt,  const int* __restrict__ list,
                      float* __restrict__ idx_f,    int* __restrict__ idx_i)
{
    __shared__ float xs[8][DIN];
    __shared__ float h1s[8][DHID];
    __shared__ float zs[8][DCODE];
    __shared__ float swd[8][8];
    __shared__ int   swi[8][8];
    __shared__ int   rls[8];
    const int t = threadIdx.x;
    const int n = *cnt;

    for (int base = blockIdx.x * 8; base < n; base += gridDim.x * 8) {
        __syncthreads();
        if (t < 8) rls[t] = (base + t < n) ? list[base + t] : -1;
        __syncthreads();
        #pragma unroll
        for (int rr = 0; rr < 8; rr++) {
            int row = rls[rr];
            if (row >= 0)
                for (int i = t; i < DIN; i += 512)
                    xs[rr][i] = x[(size_t)row * DIN + i];
        }
        __syncthreads();
        {
            float acc[8] = {0.f,0.f,0.f,0.f,0.f,0.f,0.f,0.f};
            for (int i = 0; i < DIN; i++) {
                float w = W1[(size_t)i * DHID + t];
                #pragma unroll
                for (int rr = 0; rr < 8; rr++)
                    acc[rr] = fmaf(xs[rr][i], w, acc[rr]);
            }
            float bb = b1[t];
            #pragma unroll
            for (int rr = 0; rr < 8; rr++)
                h1s[rr][t] = fmaxf(__fadd_rn(acc[rr], bb), 0.f);
        }
        __syncthreads();
        {
            int half = t >> 8, t2 = t & 255;
            float acc[4] = {0.f,0.f,0.f,0.f};
            for (int h = 0; h < DHID; h++) {
                float w = W2[(size_t)h * DCODE + t2];
                #pragma unroll
                for (int q2 = 0; q2 < 4; q2++)
                    acc[q2] = fmaf(h1s[half * 4 + q2][h], w, acc[q2]);
            }
            float bb = b2[t2];
            #pragma unroll
            for (int q2 = 0; q2 < 4; q2++)
                zs[half * 4 + q2][t2] = __fadd_rn(acc[q2], bb);
        }
        __syncthreads();
        {
            float acc[8] = {0.f,0.f,0.f,0.f,0.f,0.f,0.f,0.f};
            for (int d = 0; d < DCODE; d++) {
                float c = cbT[(size_t)d * KC + t];
                #pragma unroll
                for (int rr = 0; rr < 8; rr++)
                    acc[rr] = fmaf(zs[rr][d], c, acc[rr]);
            }
            float cn = cnorm[t];
            #pragma unroll
            for (int rr = 0; rr < 8; rr++) {
                float d = __fsub_rn(cn, __fmul_rn(2.0f, acc[rr]));
                int ii = t;
                #pragma unroll
                for (int m = 1; m < 64; m <<= 1) {
                    float od = __shfl_xor(d, m);
                    int   oi = __shfl_xor(ii, m);
                    if (od < d || (od == d && oi < ii)) { d = od; ii = oi; }
                }
                if ((t & 63) == 0) { swd[rr][t >> 6] = d; swi[rr][t >> 6] = ii; }
            }
        }
        __syncthreads();
        if (t < 8) {
            int row = rls[t];
            if (row >= 0) {
                float d = swd[t][0]; int ii = swi[t][0];
                #pragma unroll
                for (int w = 1; w < 8; w++) {
                    float od = swd[t][w]; int oi = swi[t][w];
                    if (od < d || (od == d && oi < ii)) { d = od; ii = oi; }
                }
                idx_i[row] = ii;
                idx_f[row] = (float)ii;
            }
        }
    }
}

// ---------------------------------------------------------------------------
__global__ void loss_reduce_kernel(const float* __restrict__ rowloss,
                                   double* __restrict__ acc, int n)
{
    double s = 0.0;
    for (int i = blockIdx.x * blockDim.x + threadIdx.x; i < n; i += gridDim.x * blockDim.x)
        s += (double)rowloss[i];
    for (int off = 32; off; off >>= 1) s += __shfl_xor(s, off);
    __shared__ double red[4];
    int lane = threadIdx.x & 63, wave = threadIdx.x >> 6;
    if (lane == 0) red[wave] = s;
    __syncthreads();
    if (threadIdx.x == 0) {
        double b = red[0] + red[1] + red[2] + red[3];
        atomicAdd(acc, b);
    }
}

__global__ void finalize_kernel(const double* __restrict__ acc, float* __restrict__ out)
{
    out[0] = (float)(acc[0] / ((double)N_ROWS * (double)DCODE));
}

// ---------------------------------------------------------------------------
extern "C" void kernel_launch(void* const* d_in, const int* in_sizes, int n_in,
                              void* d_out, int out_size, void* d_ws, size_t ws_size,
                              hipStream_t stream)
{
    const float* x  = (const float*)d_in[0];
    const float* W1 = (const float*)d_in[1];
    const float* b1 = (const float*)d_in[2];
    const float* W2 = (const float*)d_in[3];
    const float* b2 = (const float*)d_in[4];
    const float* cb = (const float*)d_in[5];
    const float* W3 = (const float*)d_in[6];
    const float* b3 = (const float*)d_in[7];
    const float* W4 = (const float*)d_in[8];
    const float* b4 = (const float*)d_in[9];
    float* out = (float*)d_out;
    char*  ws  = (char*)d_ws;

    u16*    h1b     = (u16*)   (ws);                      // 134217728
    float*  pd1     = (float*) (ws + 134217728);          // 4194304
    int*    pi1     = (int*)   (ws + 138412032);          // 4194304
    float*  pd2     = (float*) (ws + 142606336);          // 4194304
    float*  pzn     = (float*) (ws + 146800640);          // 2097152
    float*  pd1b    = (float*) (ws + 148897792);          // 1048576 (8 x CAP)
    int*    pi1b    = (int*)   (ws + 149946368);          // 1048576
    float*  pd2b    = (float*) (ws + 150994944);          // 1048576
    float*  xg      = (float*) (ws + 152043520);          // 100663296
    u16*    h1ghi   = (u16*)   (ws + 252706816);          // 33554432
    u16*    h1glo   = (u16*)   (ws + 286261248);          // 33554432
    float*  rowloss = (float*) (ws + 319815680);          // 524288
    int*    idxi    = (int*)   (ws + 320339968);          // 524288
    int*    list    = (int*)   (ws + 320864256);          // 524288
    int*    list2   = (int*)   (ws + 321388544);          // 524288
    int*    rcnt1   = (int*)   (ws + 321912832);          // 4
    int*    rcnt2   = (int*)   (ws + 321912836);          // 4
    double* lossa   = (double*)(ws + 321912896);          // 8
    u16*    W1Thi   = (u16*)   (ws + 321912960);          // 786432
    u16*    W1Tlo   = (u16*)   (ws + 322699392);          // 786432
    u16*    Wfb     = (u16*)   (ws + 323485824);          // 786432 (768x512)
    u16*    WfTlo   = (u16*)   (ws + 324272256);          // 524288 (512x512)
    u16*    cbB     = (u16*)   (ws + 324796544);          // 262144
    u16*    W3T     = (u16*)   (ws + 325058688);          // 262144
    u16*    W4T     = (u16*)   (ws + 325320832);          // 786432
    float*  bcf     = (float*) (ws + 326107264);          // 3072
    float*  cnorm   = (float*) (ws + 326110336);          // 2048
    float*  cbT     = (float*) (ws + 326112384);          // 524288
    u16*    R1b     = (u16*)   (ws + 326636672);          // 524288
    float*  Rf      = (float*) (ws + 327160960);          // 1572864

    float* idxf    = out + (size_t)N_ROWS * DIN;
    float* lossout = idxf + N_ROWS;

    hipMemsetAsync(ws + 321912832, 0, 128, stream);       // rcnt1/rcnt2/lossa

    // prep
    transpose_cb_kernel<<<512, 256, 0, stream>>>(cb, cbT);
    cnorm_np_kernel<<<8, 64, 0, stream>>>(cb, cnorm);
    cast_bf16_kernel<<<(KC*DCODE)/256, 256, 0, stream>>>(cb, cbB, KC*DCODE);
    castT_bf16_kernel<<<(DCODE*DHID)/256, 256, 0, stream>>>(W3, W3T, DCODE, DHID);
    castT_bf16_kernel<<<(DHID*DIN)/256, 256, 0, stream>>>(W4, W4T, DHID, DIN);
    prep_W1T<<<(DHID*DIN)/256, 256, 0, stream>>>(W1, W1Thi, W1Tlo);
    prep_Wc<<<(KC*DHID)/256, 256, 0, stream>>>(W2, cb, Wfb, WfTlo);
    prep_W2T<<<(DCODE*DHID)/256, 256, 0, stream>>>(W2, Wfb);
    prep_bcf<<<3, 256, 0, stream>>>(b2, cb, bcf);

    // decoder table R[512][768] = relu(cb@W3+b3)@W4+b4
    mfma_gemm<true,  true ><<<dim3(4, 4), 256, 0, stream>>>(
        cbB, W3T, b3, (void*)R1b, KC, DHID, DCODE);
    mfma_gemm<false, false><<<dim3(6, 4), 256, 0, stream>>>(
        R1b, W4T, b4, (void*)Rf, KC, DIN, DHID);

    // tier-1: plain bf16 h1, then plain-bf16 dots+znorm, flag gap < TAU1
    h1_plain<<<dim3(DHID/128, N_ROWS/128), 256, 0, stream>>>(
        x, W1Thi, b1, h1b, N_ROWS, DHID, DIN);
    dots_gemm<<<dim3(NFUSE/128, N_ROWS/128), 256, 0, stream>>>(
        h1b, Wfb, bcf, cnorm, pd1, pi1, pd2, pzn, N_ROWS, NFUSE, DHID);
    final_argmin_flag<<<N_ROWS/256, 256, 0, stream>>>(
        pd1, pi1, pd2, pzn, idxf, idxi, rowloss, rcnt1, list);

    // tier-2: gathered split-2 h1 + split-2 dots on contested rows
    // (early-exit on rcnt1 makes cost scale with actual contested count)
    gather_x<<<2048, 256, 0, stream>>>(x, list, rcnt1, xg);
    split2_gemm<0><<<dim3(DHID/128, CAP/128), 256, 0, stream>>>(
        xg, nullptr, nullptr, W1Thi, W1Tlo, b1, nullptr,
        h1ghi, h1glo, nullptr, nullptr, nullptr, rcnt1, CAP, DHID, DIN);
    split2_gemm<1><<<dim3(KC/128, CAP/128), 256, 0, stream>>>(
        nullptr, h1ghi, h1glo, Wfb, WfTlo, bcf, cnorm,
        nullptr, nullptr, pd1b, pi1b, pd2b, rcnt1, CAP, KC, DHID);
    merge2_flag<<<CAP/256, 256, 0, stream>>>(
        pd1b, pi1b, pd2b, list, rcnt1, idxf, idxi, rcnt2, list2);
    overflow_append<<<(N_ROWS-CAP)/256, 256, 0, stream>>>(list, rcnt1, rcnt2, list2);

    // tier-3: bitwise recompute of the tiny remainder
    recompute_kernel<<<2048, 512, 0, stream>>>(
        x, W1, b1, W2, b2, cbT, cnorm, rcnt2, list2, idxf, idxi);

    // recon = R[idx] broadcast-gather
    gather_out<<<4096, 256, 0, stream>>>(Rf, idxi, out);

    loss_reduce_kernel<<<256, 256, 0, stream>>>(rowloss, lossa, N_ROWS);
    finalize_kernel<<<1, 1, 0, stream>>>(lossa, lossout);
}

// Round 16
// 874.121 us; speedup vs baseline: 1.0840x; 1.0840x over previous
//
#include <hip/hip_runtime.h>
#include <hip/hip_bf16.h>
#include <math.h>

#define N_ROWS 131072
#define DIN    768
#define DHID   512
#define DCODE  256
#define KC     512
#define NFUSE  768      // KC + DCODE (dots cols + z cols)
#define TAU1   1.5f     // tier-1 screen (plain h1 + plain dots; validated r9/r13)
#define TAU2   5e-3f    // tier-2 screen (split-2 numerics; validated r6/7/8/10)
#define CAP    32768    // tier-2 row capacity (overflow -> bitwise recompute)

typedef short short8 __attribute__((ext_vector_type(8)));
typedef float f32x4  __attribute__((ext_vector_type(4)));
typedef unsigned int   u32;
typedef unsigned short u16;

__device__ __forceinline__ void gload16(const void* g, void* l) {
    __builtin_amdgcn_global_load_lds(
        (const __attribute__((address_space(1))) u32*)g,
        (__attribute__((address_space(3))) u32*)l, 16, 0, 0);
}

__device__ __forceinline__ u16 f2bf(float f) {
    u32 u = __builtin_bit_cast(u32, f);
    return (u16)((u + 0x7fffu + ((u >> 16) & 1u)) >> 16);
}
__device__ __forceinline__ float bf2f(u16 h) {
    u32 u = ((u32)h) << 16;
    return __builtin_bit_cast(float, u);
}

// m157-form bijective XCD swizzle (all grids have nwg % 8 == 0)
__device__ __forceinline__ void xcd_swizzle(int& bxs, int& bys) {
    const int GX  = gridDim.x;
    const int nwg = GX * gridDim.y;
    const int lid = blockIdx.y * GX + blockIdx.x;
    const int chunk = nwg >> 3;
    const int nlid  = (lid & 7) * chunk + (lid >> 3);
    bxs = nlid % GX;
    bys = nlid / GX;
}

// hi/lo bf16 split of a float4, written to two 8B LDS slots
__device__ __forceinline__ void split_write(char* hidst, char* lodst, float4 v) {
    u16 h0 = f2bf(v.x), h1 = f2bf(v.y), h2 = f2bf(v.z), h3 = f2bf(v.w);
    u16 l0 = f2bf(__fsub_rn(v.x, bf2f(h0)));
    u16 l1 = f2bf(__fsub_rn(v.y, bf2f(h1)));
    u16 l2 = f2bf(__fsub_rn(v.z, bf2f(h2)));
    u16 l3 = f2bf(__fsub_rn(v.w, bf2f(h3)));
    ushort4 hi; hi.x = h0; hi.y = h1; hi.z = h2; hi.w = h3;
    ushort4 lo; lo.x = l0; lo.y = l1; lo.z = l2; lo.w = l3;
    *(ushort4*)hidst = hi;
    *(ushort4*)lodst = lo;
}

// ---------------------------------------------------------------------------
// Tier-1 H1: plain bf16 MFMA, f32 A-source (r13-proven sw cvt + swizzled
// ds_write). 128x128, BK=64, single-buffer 32KB, (256,3): 230us @ 84 VGPR.
// ---------------------------------------------------------------------------
__global__ __launch_bounds__(256, 3)
void h1_plain(const float* __restrict__ x, const u16* __restrict__ W1T,
              const float* __restrict__ b1, u16* __restrict__ h1b,
              int M, int N, int K)
{
    __shared__ char lds[32768];
    const int t = threadIdx.x, lane = t & 63, wid = t >> 6;
    const int wm = wid >> 1, wn = wid & 1;
    int bxs, bys; xcd_swizzle(bxs, bys);
    const int bm = bys * 128, bn = bxs * 128;

    const int sr = lane >> 3;
    const int sc = ((lane & 7) ^ sr) * 8;
    const u16* bptr[4];
    #pragma unroll
    for (int c = 0; c < 4; c++) {
        int brow = bn + 8 * (wid * 4 + c) + sr;
        bptr[c] = W1T + (size_t)brow * K + sc;
    }
    const float* asrc[4];
    int albyte[4];
    #pragma unroll
    for (int c = 0; c < 4; c++) {
        int id = c * 256 + t;           // row(0..127) x slot(0..7)
        int row = id >> 3, g = id & 7;
        asrc[c]   = x + (size_t)(bm + row) * K + g * 8;
        albyte[c] = row * 128 + ((g ^ (row & 7)) << 4);
    }

    f32x4 acc[4][4];
    #pragma unroll
    for (int i = 0; i < 4; i++)
        #pragma unroll
        for (int j = 0; j < 4; j++) acc[i][j] = (f32x4)0.f;

    const int koff0 = (16 * (lane >> 4))      ^ ((lane & 7) << 4);
    const int koff1 = (64 + 16 * (lane >> 4)) ^ ((lane & 7) << 4);
    const int arow_rd = wm * 64 + (lane & 15);
    const int brow_rd = wn * 64 + (lane & 15);

    const int NT = K >> 6;   // 12
    for (int tt = 0; tt < NT; tt++) {
        __syncthreads();
        const int k0 = tt << 6;
        #pragma unroll
        for (int c = 0; c < 4; c++)
            gload16(bptr[c] + k0, lds + 16384 + (wid * 4 + c) * 1024);
        #pragma unroll
        for (int c = 0; c < 4; c++) {
            float4 v0 = *(const float4*)(asrc[c] + k0);
            float4 v1 = *(const float4*)(asrc[c] + k0 + 4);
            short8 p;
            p[0] = (short)f2bf(v0.x); p[1] = (short)f2bf(v0.y);
            p[2] = (short)f2bf(v0.z); p[3] = (short)f2bf(v0.w);
            p[4] = (short)f2bf(v1.x); p[5] = (short)f2bf(v1.y);
            p[6] = (short)f2bf(v1.z); p[7] = (short)f2bf(v1.w);
            *(short8*)(lds + albyte[c]) = p;
        }
        __syncthreads();
        char* ldsA = lds;
        char* ldsB = lds + 16384;
        #pragma unroll
        for (int kk = 0; kk < 2; kk++) {
            const int ko = kk ? koff1 : koff0;
            short8 af[4], bfr[4];
            #pragma unroll
            for (int i = 0; i < 4; i++)
                af[i]  = *(const short8*)(ldsA + (arow_rd + i * 16) * 128 + ko);
            #pragma unroll
            for (int j = 0; j < 4; j++)
                bfr[j] = *(const short8*)(ldsB + (brow_rd + j * 16) * 128 + ko);
            #pragma unroll
            for (int i = 0; i < 4; i++)
                #pragma unroll
                for (int j = 0; j < 4; j++)
                    acc[i][j] = __builtin_amdgcn_mfma_f32_16x16x32_bf16(
                        af[i], bfr[j], acc[i][j], 0, 0, 0);
        }
    }

    const int er = (lane >> 4) * 4, ec = lane & 15;
    #pragma unroll
    for (int j = 0; j < 4; j++) {
        int col  = bn + wn * 64 + j * 16 + ec;
        float bb = b1[col];
        #pragma unroll
        for (int i = 0; i < 4; i++) {
            #pragma unroll
            for (int e = 0; e < 4; e++) {
                int r   = bm + wm * 64 + i * 16 + er + e;
                float v = fmaxf(acc[i][j][e] + bb, 0.f);
                h1b[(size_t)r * N + col] = f2bf(v);
            }
        }
    }
}

// ---------------------------------------------------------------------------
// Split-2 bf16 MFMA GEMM (tier-2 only). 128x128, BK=32, 32KB LDS, (256,3).
// ecnt: early-exit row count (blocks with bm >= *ecnt return before any
// barrier, making tier-2 cost scale with the actual contested count).
// EPI=0: A = f32 (gathered x), epilogue relu+bias -> hi/lo bf16.
// EPI=1: A = bf16 hi/lo pair; epilogue dist top-2 lex-min strip partials.
// ---------------------------------------------------------------------------
template<int EPI>
__global__ __launch_bounds__(256, 3)
void split2_gemm(const float* __restrict__ Af32,
                 const u16* __restrict__ Ahi, const u16* __restrict__ Alo,
                 const u16* __restrict__ Bhi, const u16* __restrict__ Blo,
                 const float* __restrict__ bias,
                 const float* __restrict__ cnorm,
                 u16* __restrict__ Chi, u16* __restrict__ Clo,
                 float* __restrict__ pd1, int* __restrict__ pi1,
                 float* __restrict__ pd2,
                 const int* __restrict__ ecnt,
                 int M, int N, int K)
{
    __shared__ char lds[32768];
    const int t = threadIdx.x, lane = t & 63, wid = t >> 6;
    const int wm = wid >> 1, wn = wid & 1;
    int bxs, bys; xcd_swizzle(bxs, bys);
    const int bm = bys * 128, bn = bxs * 128;
    if (ecnt && bm >= *ecnt) return;   // uniform early-exit (before any barrier)

    const int sr = lane >> 3, qq = lane & 7, sl = qq ^ sr;
    const u16* bsrc[4];
    #pragma unroll
    for (int c = 0; c < 4; c++) {
        int row = bn + (wid * 4 + c) * 8 + sr;
        const u16* base = (sl < 4) ? Bhi : Blo;
        bsrc[c] = base + (size_t)row * K + (sl & 3) * 8;
    }
    const u16* asrc[4];
    const float* a32src[4];
    int adhi[4], adlo[4];
    if constexpr (EPI == 1) {
        #pragma unroll
        for (int c = 0; c < 4; c++) {
            int row = bm + (wid * 4 + c) * 8 + sr;
            const u16* base = (sl < 4) ? Ahi : Alo;
            asrc[c] = base + (size_t)row * K + (sl & 3) * 8;
        }
    } else {
        #pragma unroll
        for (int c = 0; c < 4; c++) {
            int id = c * 256 + t;
            int row = id >> 3, k4 = id & 7;
            a32src[c] = Af32 + (size_t)(bm + row) * K + k4 * 4;
            int s = k4 >> 1, hf = k4 & 1;
            adhi[c] = row * 128 + ((s ^ (row & 7)) << 4) + hf * 8;
            adlo[c] = row * 128 + (((s | 4) ^ (row & 7)) << 4) + hf * 8;
        }
    }

    f32x4 acc[4][4];
    #pragma unroll
    for (int i = 0; i < 4; i++)
        #pragma unroll
        for (int j = 0; j < 4; j++) acc[i][j] = (f32x4)0.f;

    const int fr = lane & 15, sw = lane & 7;
    const int offhi = (((lane >> 4) ^ sw) << 4);
    const int offlo = ((((lane >> 4) | 4) ^ sw) << 4);
    const int arow = wm * 64 + fr, brow = wn * 64 + fr;
    const int NT = K >> 5;

    for (int tt = 0; tt < NT; tt++) {
        __syncthreads();
        const int kadv = tt * 32;
        #pragma unroll
        for (int c = 0; c < 4; c++)
            gload16(bsrc[c] + kadv, lds + 16384 + (wid * 4 + c) * 1024);
        if constexpr (EPI == 1) {
            #pragma unroll
            for (int c = 0; c < 4; c++)
                gload16(asrc[c] + kadv, lds + (wid * 4 + c) * 1024);
        } else {
            #pragma unroll
            for (int c = 0; c < 4; c++) {
                float4 v = *(const float4*)(a32src[c] + kadv);
                split_write(lds + adhi[c], lds + adlo[c], v);
            }
        }
        __syncthreads();
        char* ab  = lds;
        char* bb2 = lds + 16384;
        short8 ah[4], al[4];
        #pragma unroll
        for (int i = 0; i < 4; i++) {
            ah[i] = *(const short8*)(ab + ((arow + i * 16) << 7) + offhi);
            al[i] = *(const short8*)(ab + ((arow + i * 16) << 7) + offlo);
        }
        #pragma unroll
        for (int j = 0; j < 4; j++) {
            short8 bh = *(const short8*)(bb2 + ((brow + j * 16) << 7) + offhi);
            short8 bl = *(const short8*)(bb2 + ((brow + j * 16) << 7) + offlo);
            #pragma unroll
            for (int i = 0; i < 4; i++) {
                acc[i][j] = __builtin_amdgcn_mfma_f32_16x16x32_bf16(ah[i], bh, acc[i][j], 0, 0, 0);
                acc[i][j] = __builtin_amdgcn_mfma_f32_16x16x32_bf16(al[i], bh, acc[i][j], 0, 0, 0);
                acc[i][j] = __builtin_amdgcn_mfma_f32_16x16x32_bf16(ah[i], bl, acc[i][j], 0, 0, 0);
            }
        }
    }

    if constexpr (EPI == 1) {
        const int ec = lane & 15, g = lane >> 4;
        float cnv[4], bcv[4];
        #pragma unroll
        for (int j = 0; j < 4; j++) {
            int c = bn + wn * 64 + j * 16 + ec;
            cnv[j] = cnorm[c]; bcv[j] = bias[c];
        }
        const int strip = bxs * 2 + wn;
        #pragma unroll
        for (int i = 0; i < 4; i++) {
            #pragma unroll
            for (int e = 0; e < 4; e++) {
                float d1 = INFINITY, d2 = INFINITY; int i1 = 0x7fffffff;
                #pragma unroll
                for (int j = 0; j < 4; j++) {
                    int c = bn + wn * 64 + j * 16 + ec;
                    float d = __fsub_rn(cnv[j],
                              __fmul_rn(2.0f, __fadd_rn(acc[i][j][e], bcv[j])));
                    if (d < d1 || (d == d1 && c < i1)) { d2 = d1; d1 = d; i1 = c; }
                    else if (d < d2) d2 = d;
                }
                #pragma unroll
                for (int m = 1; m < 16; m <<= 1) {
                    float od1 = __shfl_xor(d1, m);
                    int   oi1 = __shfl_xor(i1, m);
                    float od2 = __shfl_xor(d2, m);
                    if (od1 < d1 || (od1 == d1 && oi1 < i1)) {
                        d2 = fminf(d1, od2); d1 = od1; i1 = oi1;
                    } else d2 = fminf(d2, od1);
                }
                if (ec == 0) {
                    int r = bm + wm * 64 + i * 16 + g * 4 + e;
                    pd1[(size_t)strip * M + r] = d1;
                    pi1[(size_t)strip * M + r] = i1;
                    pd2[(size_t)strip * M + r] = d2;
                }
            }
        }
        return;
    } else {
        const int er = (lane >> 4) * 4, ec = lane & 15;
        #pragma unroll
        for (int j = 0; j < 4; j++) {
            int col = bn + wn * 64 + j * 16 + ec;
            float bb = bias[col];
            #pragma unroll
            for (int i = 0; i < 4; i++) {
                #pragma unroll
                for (int e = 0; e < 4; e++) {
                    int r = bm + wm * 64 + i * 16 + er + e;
                    float v = fmaxf(__fadd_rn(acc[i][j][e], bb), 0.f);
                    u16 hi = f2bf(v);
                    u16 lo = f2bf(__fsub_rn(v, bf2f(hi)));
                    Chi[(size_t)r * N + col] = hi;
                    Clo[(size_t)r * N + col] = lo;
                }
            }
        }
    }
}

// ---------------------------------------------------------------------------
// Tier-1 DOTS+Z: plain bf16 MFMA on h1b. 128x128, BK=64, 32KB, (256,3).
// Col-blocks 0-3: dist top-2 strip partials. Col-blocks 4-5: znorm partials.
// ---------------------------------------------------------------------------
__global__ __launch_bounds__(256, 3)
void dots_gemm(const u16* __restrict__ A, const u16* __restrict__ BT,
               const float* __restrict__ bias, const float* __restrict__ cnorm,
               float* __restrict__ pd1, int* __restrict__ pi1,
               float* __restrict__ pd2, float* __restrict__ pzn,
               int M, int N, int K)
{
    __shared__ char lds[32768];
    const int t = threadIdx.x, lane = t & 63, wid = t >> 6;
    const int wm = wid >> 1, wn = wid & 1;
    int bxs, bys; xcd_swizzle(bxs, bys);
    const int bm = bys * 128, bn = bxs * 128;

    const int sr = lane >> 3;
    const int sc = ((lane & 7) ^ sr) * 8;
    const u16* aptr[4];
    const u16* bptr[4];
    #pragma unroll
    for (int c = 0; c < 4; c++) {
        int gc = wid * 4 + c;
        aptr[c] = A  + (size_t)(bm + 8 * gc + sr) * K + sc;
        bptr[c] = BT + (size_t)(bn + 8 * gc + sr) * K + sc;
    }

    f32x4 acc[4][4];
    #pragma unroll
    for (int i = 0; i < 4; i++)
        #pragma unroll
        for (int j = 0; j < 4; j++) acc[i][j] = (f32x4)0.f;

    const int koff0 = (16 * (lane >> 4))      ^ ((lane & 7) << 4);
    const int koff1 = (64 + 16 * (lane >> 4)) ^ ((lane & 7) << 4);
    const int arow_rd = wm * 64 + (lane & 15);
    const int brow_rd = wn * 64 + (lane & 15);

    const int NT = K >> 6;   // 8
    for (int tt = 0; tt < NT; tt++) {
        __syncthreads();
        const int k0 = tt << 6;
        #pragma unroll
        for (int c = 0; c < 4; c++) {
            int gc = wid * 4 + c;
            gload16(aptr[c] + k0, lds + gc * 1024);
            gload16(bptr[c] + k0, lds + 16384 + gc * 1024);
        }
        __syncthreads();
        char* ldsA = lds;
        char* ldsB = lds + 16384;
        #pragma unroll
        for (int kk = 0; kk < 2; kk++) {
            const int ko = kk ? koff1 : koff0;
            short8 af[4], bfr[4];
            #pragma unroll
            for (int i = 0; i < 4; i++)
                af[i]  = *(const short8*)(ldsA + (arow_rd + i * 16) * 128 + ko);
            #pragma unroll
            for (int j = 0; j < 4; j++)
                bfr[j] = *(const short8*)(ldsB + (brow_rd + j * 16) * 128 + ko);
            #pragma unroll
            for (int i = 0; i < 4; i++)
                #pragma unroll
                for (int j = 0; j < 4; j++)
                    acc[i][j] = __builtin_amdgcn_mfma_f32_16x16x32_bf16(
                        af[i], bfr[j], acc[i][j], 0, 0, 0);
        }
    }

    const int ec = lane & 15, g = lane >> 4;
    if (bxs < 4) {
        float cnv[4], bcv[4];
        #pragma unroll
        for (int j = 0; j < 4; j++) {
            int c = bn + wn * 64 + j * 16 + ec;
            cnv[j] = cnorm[c]; bcv[j] = bias[c];
        }
        const int strip = bxs * 2 + wn;
        #pragma unroll
        for (int i = 0; i < 4; i++) {
            #pragma unroll
            for (int e = 0; e < 4; e++) {
                float d1 = INFINITY, d2 = INFINITY; int i1 = 0x7fffffff;
                #pragma unroll
                for (int j = 0; j < 4; j++) {
                    int c = bn + wn * 64 + j * 16 + ec;
                    float d = __fsub_rn(cnv[j],
                              __fmul_rn(2.0f, __fadd_rn(acc[i][j][e], bcv[j])));
                    if (d < d1 || (d == d1 && c < i1)) { d2 = d1; d1 = d; i1 = c; }
                    else if (d < d2) d2 = d;
                }
                #pragma unroll
                for (int m = 1; m < 16; m <<= 1) {
                    float od1 = __shfl_xor(d1, m);
                    int   oi1 = __shfl_xor(i1, m);
                    float od2 = __shfl_xor(d2, m);
                    if (od1 < d1 || (od1 == d1 && oi1 < i1)) {
                        d2 = fminf(d1, od2); d1 = od1; i1 = oi1;
                    } else d2 = fminf(d2, od1);
                }
                if (ec == 0) {
                    int r = bm + wm * 64 + i * 16 + g * 4 + e;
                    pd1[(size_t)strip * M + r] = d1;
                    pi1[(size_t)strip * M + r] = i1;
                    pd2[(size_t)strip * M + r] = d2;
                }
            }
        }
    } else {
        float bcv[4];
        #pragma unroll
        for (int j = 0; j < 4; j++)
            bcv[j] = bias[bn + wn * 64 + j * 16 + ec];
        const int zs = (bxs - 4) * 2 + wn;
        #pragma unroll
        for (int i = 0; i < 4; i++) {
            #pragma unroll
            for (int e = 0; e < 4; e++) {
                float s = 0.f;
                #pragma unroll
                for (int j = 0; j < 4; j++) {
                    float zv = acc[i][j][e] + bcv[j];
                    s = fmaf(zv, zv, s);
                }
                #pragma unroll
                for (int m = 1; m < 16; m <<= 1) s += __shfl_xor(s, m);
                if (ec == 0) {
                    int r = bm + wm * 64 + i * 16 + g * 4 + e;
                    pzn[(size_t)zs * M + r] = s;
                }
            }
        }
    }
}

// ---------------------------------------------------------------------------
// Plain bf16 MFMA GEMM (tiny R-table GEMMs; lenient).
// ---------------------------------------------------------------------------
template<bool RELU, bool OUT_BF16>
__global__ __launch_bounds__(256, 3)
void mfma_gemm(const u16* __restrict__ A, const u16* __restrict__ BT,
               const float* __restrict__ bias,
               void* __restrict__ Cout, int M, int N, int K)
{
    __shared__ char lds[32768];
    const int t    = threadIdx.x;
    const int lane = t & 63, wid = t >> 6;
    const int wm   = wid >> 1, wn = wid & 1;
    int bxs, bys;
    xcd_swizzle(bxs, bys);
    const int bm = bys * 128, bn = bxs * 128;

    const int sr = lane >> 3;
    const int sc = ((lane & 7) ^ sr) * 8;
    const u16* aptr[4];
    const u16* bptr[4];
    #pragma unroll
    for (int c = 0; c < 4; c++) {
        int gc   = wid * 4 + c;
        aptr[c] = A  + (size_t)(bm + 8 * gc + sr) * K + sc;
        bptr[c] = BT + (size_t)(bn + 8 * gc + sr) * K + sc;
    }

    f32x4 acc[4][4];
    #pragma unroll
    for (int i = 0; i < 4; i++)
        #pragma unroll
        for (int j = 0; j < 4; j++) acc[i][j] = (f32x4)0.f;

    const int koff0 = (16 * (lane >> 4))      ^ ((lane & 7) << 4);
    const int koff1 = (64 + 16 * (lane >> 4)) ^ ((lane & 7) << 4);
    const int arow_rd = wm * 64 + (lane & 15);
    const int brow_rd = wn * 64 + (lane & 15);

    const int NT = K >> 6;
    for (int tt = 0; tt < NT; tt++) {
        __syncthreads();
        const int k0 = tt << 6;
        #pragma unroll
        for (int c = 0; c < 4; c++) {
            int gc = wid * 4 + c;
            gload16(aptr[c] + k0, lds + gc * 1024);
            gload16(bptr[c] + k0, lds + 16384 + gc * 1024);
        }
        __syncthreads();
        char* ldsA = lds;
        char* ldsB = lds + 16384;
        #pragma unroll
        for (int kk = 0; kk < 2; kk++) {
            const int ko = kk ? koff1 : koff0;
            short8 af[4], bfr[4];
            #pragma unroll
            for (int i = 0; i < 4; i++)
                af[i]  = *(const short8*)(ldsA + (arow_rd + i * 16) * 128 + ko);
            #pragma unroll
            for (int j = 0; j < 4; j++)
                bfr[j] = *(const short8*)(ldsB + (brow_rd + j * 16) * 128 + ko);
            #pragma unroll
            for (int i = 0; i < 4; i++)
                #pragma unroll
                for (int j = 0; j < 4; j++)
                    acc[i][j] = __builtin_amdgcn_mfma_f32_16x16x32_bf16(
                        af[i], bfr[j], acc[i][j], 0, 0, 0);
        }
    }

    const int er = (lane >> 4) * 4;
    const int ec = lane & 15;
    #pragma unroll
    for (int j = 0; j < 4; j++) {
        int col  = bn + wn * 64 + j * 16 + ec;
        float bb = bias[col];
        #pragma unroll
        for (int i = 0; i < 4; i++) {
            #pragma unroll
            for (int e = 0; e < 4; e++) {
                int r   = bm + wm * 64 + i * 16 + er + e;
                float v = acc[i][j][e] + bb;
                if (RELU) v = fmaxf(v, 0.f);
                if (OUT_BF16) ((u16*)Cout)[(size_t)r * N + col]  = f2bf(v);
                else          ((float*)Cout)[(size_t)r * N + col] = v;
            }
        }
    }
}

// ---------------------------------------------------------------------------
// recon = R[idx[r]] broadcast-gather (R is 512x768 fp32, L2-resident).
// ---------------------------------------------------------------------------
__global__ __launch_bounds__(256)
void gather_out(const float* __restrict__ R, const int* __restrict__ idxi,
                float* __restrict__ out)
{
    int w    = (blockIdx.x * 256 + threadIdx.x) >> 6;
    int lane = threadIdx.x & 63;
    int nw   = (gridDim.x * 256) >> 6;
    for (int r = w; r < N_ROWS; r += nw) {
        int code = idxi[r];
        const float4* src = (const float4*)(R + (size_t)code * DIN);
        float4* dst = (float4*)(out + (size_t)r * DIN);
        dst[lane]       = src[lane];
        dst[lane + 64]  = src[lane + 64];
        dst[lane + 128] = src[lane + 128];
    }
}

// ---------------------------------------------------------------------------
// Gather contested x rows (f32, 768 each) into compact xg (first CAP).
// ---------------------------------------------------------------------------
__global__ __launch_bounds__(256)
void gather_x(const float* __restrict__ x, const int* __restrict__ list,
              const int* __restrict__ cnt, float* __restrict__ xg)
{
    int n1 = *cnt; if (n1 > CAP) n1 = CAP;
    int w    = (blockIdx.x * 256 + threadIdx.x) >> 6;
    int lane = threadIdx.x & 63;
    int nw   = (gridDim.x * 256) >> 6;
    for (int i = w; i < n1; i += nw) {
        int row = list[i];
        const float4* src = (const float4*)(x + (size_t)row * DIN);
        float4* dst = (float4*)(xg + (size_t)i * DIN);
        dst[lane]       = src[lane];
        dst[lane + 64]  = src[lane + 64];
        dst[lane + 128] = src[lane + 128];
    }
}

// ---------------------------------------------------------------------------
// Prep kernels
// ---------------------------------------------------------------------------
__global__ void transpose_cb_kernel(const float* __restrict__ cb, float* __restrict__ cbT)
{
    int tid = blockIdx.x * 256 + threadIdx.x;   // 512*256
    int k = tid >> 8;
    int d = tid & 255;
    cbT[(size_t)d * KC + k] = cb[(size_t)k * DCODE + d];
}

__global__ void cast_bf16_kernel(const float* __restrict__ in, u16* __restrict__ out, int n)
{
    int i = blockIdx.x * 256 + threadIdx.x;
    if (i < n) out[i] = f2bf(in[i]);
}

// in [K][N] fp32 -> out [N][K] bf16
__global__ void castT_bf16_kernel(const float* __restrict__ in, u16* __restrict__ out,
                                  int K, int N)
{
    int i = blockIdx.x * 256 + threadIdx.x;
    if (i >= K * N) return;
    int n = i / K, k = i - n * K;
    out[i] = f2bf(in[(size_t)k * N + n]);
}

// W1 [768][512] -> W1T hi/lo [512][768]  (hi == plain bf16 cast)
__global__ void prep_W1T(const float* __restrict__ W1, u16* __restrict__ Thi,
                         u16* __restrict__ Tlo)
{
    int id = blockIdx.x * 256 + threadIdx.x;    // 512*768
    if (id >= DHID * DIN) return;
    int n = id / DIN, k = id - n * DIN;
    float v = W1[(size_t)k * DHID + n];
    u16 hi = f2bf(v);
    Thi[id] = hi;
    Tlo[id] = f2bf(__fsub_rn(v, bf2f(hi)));
}

// Wfb rows 0-511: Wc[n][h] = fp64 sum W2[h][t]*cb[n][t] -> hi (Wfb) + lo
__global__ void prep_Wc(const float* __restrict__ W2, const float* __restrict__ cb,
                        u16* __restrict__ Thi, u16* __restrict__ Tlo)
{
    int id = blockIdx.x * 256 + threadIdx.x;    // 512*512
    int n = id & 511, h = id >> 9;
    double acc = 0.0;
    for (int tt2 = 0; tt2 < DCODE; tt2++)
        acc += (double)W2[(size_t)h * DCODE + tt2] * (double)cb[(size_t)n * DCODE + tt2];
    float v = (float)acc;
    u16 hi = f2bf(v);
    Thi[(size_t)n * DHID + h] = hi;
    Tlo[(size_t)n * DHID + h] = f2bf(__fsub_rn(v, bf2f(hi)));
}

// Wfb rows 512-767: W2 [512][256] -> Wfb[512+t2][h] bf16 (z cols, lenient)
__global__ void prep_W2T(const float* __restrict__ W2, u16* __restrict__ T)
{
    int id = blockIdx.x * 256 + threadIdx.x;    // 256*512
    if (id >= DCODE * DHID) return;
    int t2 = id >> 9, h = id & 511;
    T[(size_t)(KC + t2) * DHID + h] = f2bf(W2[(size_t)h * DCODE + t2]);
}

// bcf[0..511] = fp64 b2·cb[n]; bcf[512..767] = b2[n-512]
__global__ void prep_bcf(const float* __restrict__ b2, const float* __restrict__ cb,
                         float* __restrict__ bcf)
{
    int n = blockIdx.x * 256 + threadIdx.x;
    if (n >= NFUSE) return;
    if (n < KC) {
        double acc = 0.0;
        for (int tt2 = 0; tt2 < DCODE; tt2++)
            acc += (double)b2[tt2] * (double)cb[(size_t)n * DCODE + tt2];
        bcf[n] = (float)acc;
    } else {
        bcf[n] = b2[n - KC];
    }
}

// ||c_k||^2 replicating numpy float32 pairwise-summation bitwise (ref-exact).
__global__ void cnorm_np_kernel(const float* __restrict__ cb, float* __restrict__ cnorm)
{
    int k = blockIdx.x * 64 + threadIdx.x;
    if (k >= KC) return;
    const float* c = cb + (size_t)k * DCODE;
    float bsum[2];
    #pragma unroll
    for (int b = 0; b < 2; b++) {
        const float* a = c + b * 128;
        float r[8];
        #pragma unroll
        for (int j = 0; j < 8; j++) r[j] = __fmul_rn(a[j], a[j]);
        for (int i = 8; i < 128; i += 8)
            #pragma unroll
            for (int j = 0; j < 8; j++)
                r[j] = __fadd_rn(r[j], __fmul_rn(a[i + j], a[i + j]));
        bsum[b] = __fadd_rn(
            __fadd_rn(__fadd_rn(r[0], r[1]), __fadd_rn(r[2], r[3])),
            __fadd_rn(__fadd_rn(r[4], r[5]), __fadd_rn(r[6], r[7])));
    }
    cnorm[k] = __fadd_rn(bsum[0], bsum[1]);
}

// ---------------------------------------------------------------------------
// Tier-1 merge of 8 strip top-2 partials + 4 znorm partials; flag gap < TAU1.
// ---------------------------------------------------------------------------
__global__ void final_argmin_flag(const float* __restrict__ pd1,
                                  const int* __restrict__ pi1,
                                  const float* __restrict__ pd2,
                                  const float* __restrict__ pzn,
                                  float* __restrict__ idx_f,
                                  int* __restrict__ idx_i,
                                  float* __restrict__ rowloss,
                                  int* __restrict__ cnt,
                                  int* __restrict__ list)
{
    int r = blockIdx.x * 256 + threadIdx.x;
    if (r >= N_ROWS) return;
    float d1 = pd1[r]; int i1 = pi1[r]; float d2 = pd2[r];
    #pragma unroll
    for (int b = 1; b < 8; b++) {
        float od1 = pd1[(size_t)b * N_ROWS + r];
        int   oi1 = pi1[(size_t)b * N_ROWS + r];
        float od2 = pd2[(size_t)b * N_ROWS + r];
        if (od1 < d1 || (od1 == d1 && oi1 < i1)) {
            d2 = fminf(d1, od2); d1 = od1; i1 = oi1;
        } else d2 = fminf(d2, od1);
    }
    float zn = pzn[r] + pzn[(size_t)N_ROWS + r]
             + pzn[(size_t)2 * N_ROWS + r] + pzn[(size_t)3 * N_ROWS + r];
    idx_f[r]   = (float)i1;
    idx_i[r]   = i1;
    rowloss[r] = zn + d1;
    if (d2 - d1 < TAU1) {
        int p = atomicAdd(cnt, 1);
        list[p] = r;
    }
}

// ---------------------------------------------------------------------------
// Tier-2 merge: resolve gathered rows from split-2 strip partials; rows with
// gap < TAU2 (plus tier-1 overflow) go to the bitwise recompute list.
// ---------------------------------------------------------------------------
__global__ void merge2_flag(const float* __restrict__ pd1b,
                            const int* __restrict__ pi1b,
                            const float* __restrict__ pd2b,
                            const int* __restrict__ list,
                            const int* __restrict__ cnt1,
                            float* __restrict__ idx_f, int* __restrict__ idx_i,
                            int* __restrict__ cnt2, int* __restrict__ list2)
{
    int i = blockIdx.x * 256 + threadIdx.x;
    if (i >= CAP) return;
    int n1 = *cnt1; if (n1 > CAP) n1 = CAP;
    if (i >= n1) return;
    float d1 = pd1b[i]; int i1 = pi1b[i]; float d2 = pd2b[i];
    #pragma unroll
    for (int b = 1; b < 8; b++) {
        float od1 = pd1b[(size_t)b * CAP + i];
        int   oi1 = pi1b[(size_t)b * CAP + i];
        float od2 = pd2b[(size_t)b * CAP + i];
        if (od1 < d1 || (od1 == d1 && oi1 < i1)) {
            d2 = fminf(d1, od2); d1 = od1; i1 = oi1;
        } else d2 = fminf(d2, od1);
    }
    int row = list[i];
    idx_f[row] = (float)i1;
    idx_i[row] = i1;
    if (d2 - d1 < TAU2) {
        int p = atomicAdd(cnt2, 1);
        list2[p] = row;
    }
}

__global__ void overflow_append(const int* __restrict__ list,
                                const int* __restrict__ cnt1,
                                int* __restrict__ cnt2, int* __restrict__ list2)
{
    int i = CAP + blockIdx.x * 256 + threadIdx.x;
    if (i < *cnt1) {
        int p = atomicAdd(cnt2, 1);
        list2[p] = list[i];
    }
}

// ---------------------------------------------------------------------------
// Bitwise fp32 recompute for contested rows (exact round-2 chain numerics).
// ---------------------------------------------------------------------------
__global__ __launch_bounds__(512)
void recompute_kernel(const float* __restrict__ x,  const float* __restrict__ W1,
                      const float* __restrict__ b1, const float* __restrict__ W2,
                      const float* __restrict__ b2, const float* __restrict__ cbT,
                      const float* __restrict__ cnorm,
                      const int* __restrict__ cnt,  const int* __restrict__ list,
                      float* __restrict__ idx_f,    int* __restrict__ idx_i)
{
    __shared__ float xs[8][DIN];
    __shared__ float h1s[8][DHID];
    __shared__ float zs[8][DCODE];
    __shared__ float swd[8][8];
    __shared__ int   swi[8][8];
    __shared__ int   rls[8];
    const int t = threadIdx.x;
    const int n = *cnt;

    for (int base = blockIdx.x * 8; base < n; base += gridDim.x * 8) {
        __syncthreads();
        if (t < 8) rls[t] = (base + t < n) ? list[base + t] : -1;
        __syncthreads();
        #pragma unroll
        for (int rr = 0; rr < 8; rr++) {
            int row = rls[rr];
            if (row >= 0)
                for (int i = t; i < DIN; i += 512)
                    xs[rr][i] = x[(size_t)row * DIN + i];
        }
        __syncthreads();
        {
            float acc[8] = {0.f,0.f,0.f,0.f,0.f,0.f,0.f,0.f};
            for (int i = 0; i < DIN; i++) {
                float w = W1[(size_t)i * DHID + t];
                #pragma unroll
                for (int rr = 0; rr < 8; rr++)
                    acc[rr] = fmaf(xs[rr][i], w, acc[rr]);
            }
            float bb = b1[t];
            #pragma unroll
            for (int rr = 0; rr < 8; rr++)
                h1s[rr][t] = fmaxf(__fadd_rn(acc[rr], bb), 0.f);
        }
        __syncthreads();
        {
            int half = t >> 8, t2 = t & 255;
            float acc[4] = {0.f,0.f,0.f,0.f};
            for (int h = 0; h < DHID; h++) {
                float w = W2[(size_t)h * DCODE + t2];
                #pragma unroll
                for (int q2 = 0; q2 < 4; q2++)
                    acc[q2] = fmaf(h1s[half * 4 + q2][h], w, acc[q2]);
            }
            float bb = b2[t2];
            #pragma unroll
            for (int q2 = 0; q2 < 4; q2++)
                zs[half * 4 + q2][t2] = __fadd_rn(acc[q2], bb);
        }
        __syncthreads();
        {
            float acc[8] = {0.f,0.f,0.f,0.f,0.f,0.f,0.f,0.f};
            for (int d = 0; d < DCODE; d++) {
                float c = cbT[(size_t)d * KC + t];
                #pragma unroll
                for (int rr = 0; rr < 8; rr++)
                    acc[rr] = fmaf(zs[rr][d], c, acc[rr]);
            }
            float cn = cnorm[t];
            #pragma unroll
            for (int rr = 0; rr < 8; rr++) {
                float d = __fsub_rn(cn, __fmul_rn(2.0f, acc[rr]));
                int ii = t;
                #pragma unroll
                for (int m = 1; m < 64; m <<= 1) {
                    float od = __shfl_xor(d, m);
                    int   oi = __shfl_xor(ii, m);
                    if (od < d || (od == d && oi < ii)) { d = od; ii = oi; }
                }
                if ((t & 63) == 0) { swd[rr][t >> 6] = d; swi[rr][t >> 6] = ii; }
            }
        }
        __syncthreads();
        if (t < 8) {
            int row = rls[t];
            if (row >= 0) {
                float d = swd[t][0]; int ii = swi[t][0];
                #pragma unroll
                for (int w = 1; w < 8; w++) {
                    float od = swd[t][w]; int oi = swi[t][w];
                    if (od < d || (od == d && oi < ii)) { d = od; ii = oi; }
                }
                idx_i[row] = ii;
                idx_f[row] = (float)ii;
            }
        }
    }
}

// ---------------------------------------------------------------------------
__global__ void loss_reduce_kernel(const float* __restrict__ rowloss,
                                   double* __restrict__ acc, int n)
{
    double s = 0.0;
    for (int i = blockIdx.x * blockDim.x + threadIdx.x; i < n; i += gridDim.x * blockDim.x)
        s += (double)rowloss[i];
    for (int off = 32; off; off >>= 1) s += __shfl_xor(s, off);
    __shared__ double red[4];
    int lane = threadIdx.x & 63, wave = threadIdx.x >> 6;
    if (lane == 0) red[wave] = s;
    __syncthreads();
    if (threadIdx.x == 0) {
        double b = red[0] + red[1] + red[2] + red[3];
        atomicAdd(acc, b);
    }
}

__global__ void finalize_kernel(const double* __restrict__ acc, float* __restrict__ out)
{
    out[0] = (float)(acc[0] / ((double)N_ROWS * (double)DCODE));
}

// ---------------------------------------------------------------------------
extern "C" void kernel_launch(void* const* d_in, const int* in_sizes, int n_in,
                              void* d_out, int out_size, void* d_ws, size_t ws_size,
                              hipStream_t stream)
{
    const float* x  = (const float*)d_in[0];
    const float* W1 = (const float*)d_in[1];
    const float* b1 = (const float*)d_in[2];
    const float* W2 = (const float*)d_in[3];
    const float* b2 = (const float*)d_in[4];
    const float* cb = (const float*)d_in[5];
    const float* W3 = (const float*)d_in[6];
    const float* b3 = (const float*)d_in[7];
    const float* W4 = (const float*)d_in[8];
    const float* b4 = (const float*)d_in[9];
    float* out = (float*)d_out;
    char*  ws  = (char*)d_ws;

    u16*    h1b     = (u16*)   (ws);                      // 134217728
    float*  pd1     = (float*) (ws + 134217728);          // 4194304
    int*    pi1     = (int*)   (ws + 138412032);          // 4194304
    float*  pd2     = (float*) (ws + 142606336);          // 4194304
    float*  pzn     = (float*) (ws + 146800640);          // 2097152
    float*  pd1b    = (float*) (ws + 148897792);          // 1048576 (8 x CAP)
    int*    pi1b    = (int*)   (ws + 149946368);          // 1048576
    float*  pd2b    = (float*) (ws + 150994944);          // 1048576
    float*  xg      = (float*) (ws + 152043520);          // 100663296
    u16*    h1ghi   = (u16*)   (ws + 252706816);          // 33554432
    u16*    h1glo   = (u16*)   (ws + 286261248);          // 33554432
    float*  rowloss = (float*) (ws + 319815680);          // 524288
    int*    idxi    = (int*)   (ws + 320339968);          // 524288
    int*    list    = (int*)   (ws + 320864256);          // 524288
    int*    list2   = (int*)   (ws + 321388544);          // 524288
    int*    rcnt1   = (int*)   (ws + 321912832);          // 4
    int*    rcnt2   = (int*)   (ws + 321912836);          // 4
    double* lossa   = (double*)(ws + 321912896);          // 8
    u16*    W1Thi   = (u16*)   (ws + 321912960);          // 786432
    u16*    W1Tlo   = (u16*)   (ws + 322699392);          // 786432
    u16*    Wfb     = (u16*)   (ws + 323485824);          // 786432 (768x512)
    u16*    WfTlo   = (u16*)   (ws + 324272256);          // 524288 (512x512)
    u16*    cbB     = (u16*)   (ws + 324796544);          // 262144
    u16*    W3T     = (u16*)   (ws + 325058688);          // 262144
    u16*    W4T     = (u16*)   (ws + 325320832);          // 786432
    float*  bcf     = (float*) (ws + 326107264);          // 3072
    float*  cnorm   = (float*) (ws + 326110336);          // 2048
    float*  cbT     = (float*) (ws + 326112384);          // 524288
    u16*    R1b     = (u16*)   (ws + 326636672);          // 524288
    float*  Rf      = (float*) (ws + 327160960);          // 1572864

    float* idxf    = out + (size_t)N_ROWS * DIN;
    float* lossout = idxf + N_ROWS;

    hipMemsetAsync(ws + 321912832, 0, 128, stream);       // rcnt1/rcnt2/lossa

    // prep
    transpose_cb_kernel<<<512, 256, 0, stream>>>(cb, cbT);
    cnorm_np_kernel<<<8, 64, 0, stream>>>(cb, cnorm);
    cast_bf16_kernel<<<(KC*DCODE)/256, 256, 0, stream>>>(cb, cbB, KC*DCODE);
    castT_bf16_kernel<<<(DCODE*DHID)/256, 256, 0, stream>>>(W3, W3T, DCODE, DHID);
    castT_bf16_kernel<<<(DHID*DIN)/256, 256, 0, stream>>>(W4, W4T, DHID, DIN);
    prep_W1T<<<(DHID*DIN)/256, 256, 0, stream>>>(W1, W1Thi, W1Tlo);
    prep_Wc<<<(KC*DHID)/256, 256, 0, stream>>>(W2, cb, Wfb, WfTlo);
    prep_W2T<<<(DCODE*DHID)/256, 256, 0, stream>>>(W2, Wfb);
    prep_bcf<<<3, 256, 0, stream>>>(b2, cb, bcf);

    // decoder table R[512][768] = relu(cb@W3+b3)@W4+b4
    mfma_gemm<true,  true ><<<dim3(4, 4), 256, 0, stream>>>(
        cbB, W3T, b3, (void*)R1b, KC, DHID, DCODE);
    mfma_gemm<false, false><<<dim3(6, 4), 256, 0, stream>>>(
        R1b, W4T, b4, (void*)Rf, KC, DIN, DHID);

    // tier-1: plain bf16 h1, then plain-bf16 dots+znorm, flag gap < TAU1
    h1_plain<<<dim3(DHID/128, N_ROWS/128), 256, 0, stream>>>(
        x, W1Thi, b1, h1b, N_ROWS, DHID, DIN);
    dots_gemm<<<dim3(NFUSE/128, N_ROWS/128), 256, 0, stream>>>(
        h1b, Wfb, bcf, cnorm, pd1, pi1, pd2, pzn, N_ROWS, NFUSE, DHID);
    final_argmin_flag<<<N_ROWS/256, 256, 0, stream>>>(
        pd1, pi1, pd2, pzn, idxf, idxi, rowloss, rcnt1, list);

    // tier-2: gathered split-2 h1 + split-2 dots on contested rows
    // (early-exit on rcnt1 makes cost scale with actual contested count)
    gather_x<<<2048, 256, 0, stream>>>(x, list, rcnt1, xg);
    split2_gemm<0><<<dim3(DHID/128, CAP/128), 256, 0, stream>>>(
        xg, nullptr, nullptr, W1Thi, W1Tlo, b1, nullptr,
        h1ghi, h1glo, nullptr, nullptr, nullptr, rcnt1, CAP, DHID, DIN);
    split2_gemm<1><<<dim3(KC/128, CAP/128), 256, 0, stream>>>(
        nullptr, h1ghi, h1glo, Wfb, WfTlo, bcf, cnorm,
        nullptr, nullptr, pd1b, pi1b, pd2b, rcnt1, CAP, KC, DHID);
    merge2_flag<<<CAP/256, 256, 0, stream>>>(
        pd1b, pi1b, pd2b, list, rcnt1, idxf, idxi, rcnt2, list2);
    overflow_append<<<(N_ROWS-CAP)/256, 256, 0, stream>>>(list, rcnt1, rcnt2, list2);

    // tier-3: bitwise recompute of the tiny remainder
    recompute_kernel<<<2048, 512, 0, stream>>>(
        x, W1, b1, W2, b2, cbT, cnorm, rcnt2, list2, idxf, idxi);

    // recon = R[idx] broadcast-gather
    gather_out<<<4096, 256, 0, stream>>>(Rf, idxi, out);

    loss_reduce_kernel<<<256, 256, 0, stream>>>(rowloss, lossa, N_ROWS);
    finalize_kernel<<<1, 1, 0, stream>>>(lossa, lossout);
}